// Round 8
// baseline (452.470 us; speedup 1.0000x reference)
//
#include <hip/hip_runtime.h>
#include <math.h>
#include <stdint.h>

// ============================================================================
// Numerics contract (DO NOT CHANGE — rounds 6/7 passed with exactly this):
//  * every sign-critical dot product = BLAS sgemm per-element DAG:
//    acc=0; for k=0..d-1 ascending: acc = fmaf(a,b,acc)  (single acc, fused)
//  * row sums = numpy pairwise_sum avx512f replica (16 leaves of 128, 8x16-lane
//    accs, ((r0+r1)+(r2+r3))+((r4+r5)+(r6+r7)), reduce_add xor-tree 8/4/2/1,
//    perfect binary tree over leaves)
//  * thr = fl(fl(wii/rs) * tv);  x = fl(fl(w/rs) - thr);  pos iff x >= 0
//  * tz sigmoid via double-exp (feeds thr -> sign-critical)
// Double-buffering / fusion below changes scheduling only, never per-element
// DAGs (kc blocks ascending, k within block ascending, same single-acc chain).
// ============================================================================

__device__ __forceinline__ float mrn(float a, float b) { return __fmul_rn(a, b); }
__device__ __forceinline__ float arn(float a, float b) { return __fadd_rn(a, b); }

#define GBK 16

// =====================================================================
// Kernel A: static mask. 128x128 tile, 8x8/thread, double-buffered LDS
// (1 barrier per kc step). mask = (S S^T > 0), FMA-chain DAG.
// =====================================================================
__global__ __launch_bounds__(256)
void mask_kernel(const float* __restrict__ S, unsigned char* __restrict__ mask,
                 int n, int d) {
  __shared__ float Xk[2][GBK][132];
  __shared__ float Yk[2][GBK][132];
  const int t = threadIdx.x, tx = t & 15, ty = t >> 4;
  const int row0 = blockIdx.y * 128, col0 = blockIdx.x * 128;
  const int r = t >> 1, q = t & 1;
  const float* xp = &S[(size_t)(row0 + r) * d + q * 8];
  const float* yp = &S[(size_t)(col0 + r) * d + q * 8];
  float acc[8][8] = {};
  float4 v0 = *reinterpret_cast<const float4*>(xp);
  float4 v1 = *reinterpret_cast<const float4*>(xp + 4);
  float4 u0 = *reinterpret_cast<const float4*>(yp);
  float4 u1 = *reinterpret_cast<const float4*>(yp + 4);
  {
    float va[8] = {v0.x, v0.y, v0.z, v0.w, v1.x, v1.y, v1.z, v1.w};
    float ua[8] = {u0.x, u0.y, u0.z, u0.w, u1.x, u1.y, u1.z, u1.w};
#pragma unroll
    for (int j = 0; j < 8; ++j) { Xk[0][q*8+j][r] = va[j]; Yk[0][q*8+j][r] = ua[j]; }
  }
  __syncthreads();
  int cur = 0;
  const int nk = d / GBK;
  for (int kc = 0; kc < nk; ++kc) {
    const bool more = (kc + 1 < nk);
    if (more) {
      xp += GBK; yp += GBK;
      v0 = *reinterpret_cast<const float4*>(xp);
      v1 = *reinterpret_cast<const float4*>(xp + 4);
      u0 = *reinterpret_cast<const float4*>(yp);
      u1 = *reinterpret_cast<const float4*>(yp + 4);
    }
    const float (*Xc)[132] = Xk[cur];
    const float (*Yc)[132] = Yk[cur];
#pragma unroll
    for (int k = 0; k < GBK; ++k) {
      float4 a0 = *reinterpret_cast<const float4*>(&Xc[k][ty * 8]);
      float4 a1 = *reinterpret_cast<const float4*>(&Xc[k][ty * 8 + 4]);
      float4 b0 = *reinterpret_cast<const float4*>(&Yc[k][tx * 4]);
      float4 b1 = *reinterpret_cast<const float4*>(&Yc[k][64 + tx * 4]);
      float a[8] = {a0.x, a0.y, a0.z, a0.w, a1.x, a1.y, a1.z, a1.w};
      float b[8] = {b0.x, b0.y, b0.z, b0.w, b1.x, b1.y, b1.z, b1.w};
#pragma unroll
      for (int i2 = 0; i2 < 8; ++i2)
#pragma unroll
        for (int j2 = 0; j2 < 8; ++j2)
          acc[i2][j2] = __builtin_fmaf(a[i2], b[j2], acc[i2][j2]);
    }
    if (more) {
      float va[8] = {v0.x, v0.y, v0.z, v0.w, v1.x, v1.y, v1.z, v1.w};
      float ua[8] = {u0.x, u0.y, u0.z, u0.w, u1.x, u1.y, u1.z, u1.w};
      int nxt = cur ^ 1;
#pragma unroll
      for (int j = 0; j < 8; ++j) { Xk[nxt][q*8+j][r] = va[j]; Yk[nxt][q*8+j][r] = ua[j]; }
      __syncthreads();
      cur = nxt;
    }
  }
#pragma unroll
  for (int i2 = 0; i2 < 8; ++i2) {
    int gi = row0 + ty * 8 + i2;
    unsigned lo = 0, hi = 0;
#pragma unroll
    for (int j2 = 0; j2 < 4; ++j2) {
      lo |= (acc[i2][j2]     > 0.0f ? 1u : 0u) << (8 * j2);
      hi |= (acc[i2][4 + j2] > 0.0f ? 1u : 0u) << (8 * j2);
    }
    *reinterpret_cast<unsigned*>(&mask[(size_t)gi * n + col0 + tx * 4])      = lo;
    *reinterpret_cast<unsigned*>(&mask[(size_t)gi * n + col0 + 64 + tx * 4]) = hi;
  }
}

// =====================================================================
// Kernel B: graph GEMM, same tiling + dbuf; w = relu(g*mask)+1e-10
// =====================================================================
__global__ __launch_bounds__(256)
void graph_kernel(const float* __restrict__ cur_, const float* __restrict__ prev,
                  const unsigned char* __restrict__ mask, float* __restrict__ wout,
                  int n, int d) {
  __shared__ float Xk[2][GBK][132];
  __shared__ float Yk[2][GBK][132];
  const int t = threadIdx.x, tx = t & 15, ty = t >> 4;
  const int row0 = blockIdx.y * 128, col0 = blockIdx.x * 128, bz = blockIdx.z;
  const float* X = cur_ + (size_t)bz * n * d;
  const float* Y = prev + (size_t)bz * n * d;
  const int r = t >> 1, q = t & 1;
  const float* xp = &X[(size_t)(row0 + r) * d + q * 8];
  const float* yp = &Y[(size_t)(col0 + r) * d + q * 8];
  float acc[8][8] = {};
  float4 v0 = *reinterpret_cast<const float4*>(xp);
  float4 v1 = *reinterpret_cast<const float4*>(xp + 4);
  float4 u0 = *reinterpret_cast<const float4*>(yp);
  float4 u1 = *reinterpret_cast<const float4*>(yp + 4);
  {
    float va[8] = {v0.x, v0.y, v0.z, v0.w, v1.x, v1.y, v1.z, v1.w};
    float ua[8] = {u0.x, u0.y, u0.z, u0.w, u1.x, u1.y, u1.z, u1.w};
#pragma unroll
    for (int j = 0; j < 8; ++j) { Xk[0][q*8+j][r] = va[j]; Yk[0][q*8+j][r] = ua[j]; }
  }
  __syncthreads();
  int cur = 0;
  const int nk = d / GBK;
  for (int kc = 0; kc < nk; ++kc) {
    const bool more = (kc + 1 < nk);
    if (more) {
      xp += GBK; yp += GBK;
      v0 = *reinterpret_cast<const float4*>(xp);
      v1 = *reinterpret_cast<const float4*>(xp + 4);
      u0 = *reinterpret_cast<const float4*>(yp);
      u1 = *reinterpret_cast<const float4*>(yp + 4);
    }
    const float (*Xc)[132] = Xk[cur];
    const float (*Yc)[132] = Yk[cur];
#pragma unroll
    for (int k = 0; k < GBK; ++k) {
      float4 a0 = *reinterpret_cast<const float4*>(&Xc[k][ty * 8]);
      float4 a1 = *reinterpret_cast<const float4*>(&Xc[k][ty * 8 + 4]);
      float4 b0 = *reinterpret_cast<const float4*>(&Yc[k][tx * 4]);
      float4 b1 = *reinterpret_cast<const float4*>(&Yc[k][64 + tx * 4]);
      float a[8] = {a0.x, a0.y, a0.z, a0.w, a1.x, a1.y, a1.z, a1.w};
      float b[8] = {b0.x, b0.y, b0.z, b0.w, b1.x, b1.y, b1.z, b1.w};
#pragma unroll
      for (int i2 = 0; i2 < 8; ++i2)
#pragma unroll
        for (int j2 = 0; j2 < 8; ++j2)
          acc[i2][j2] = __builtin_fmaf(a[i2], b[j2], acc[i2][j2]);
    }
    if (more) {
      float va[8] = {v0.x, v0.y, v0.z, v0.w, v1.x, v1.y, v1.z, v1.w};
      float ua[8] = {u0.x, u0.y, u0.z, u0.w, u1.x, u1.y, u1.z, u1.w};
      int nxt = cur ^ 1;
#pragma unroll
      for (int j = 0; j < 8; ++j) { Xk[nxt][q*8+j][r] = va[j]; Yk[nxt][q*8+j][r] = ua[j]; }
      __syncthreads();
      cur = nxt;
    }
  }
#pragma unroll
  for (int i2 = 0; i2 < 8; ++i2) {
    int gi = row0 + ty * 8 + i2;
    size_t rb = (size_t)bz * n * n + (size_t)gi * n;
    unsigned mlo = *reinterpret_cast<const unsigned*>(&mask[(size_t)gi * n + col0 + tx * 4]);
    unsigned mhi = *reinterpret_cast<const unsigned*>(&mask[(size_t)gi * n + col0 + 64 + tx * 4]);
    float4 o0, o1;
    o0.x = arn(fmaxf(mrn(acc[i2][0], (float)(mlo & 0xff)), 0.0f), 1e-10f);
    o0.y = arn(fmaxf(mrn(acc[i2][1], (float)((mlo >> 8) & 0xff)), 0.0f), 1e-10f);
    o0.z = arn(fmaxf(mrn(acc[i2][2], (float)((mlo >> 16) & 0xff)), 0.0f), 1e-10f);
    o0.w = arn(fmaxf(mrn(acc[i2][3], (float)((mlo >> 24) & 0xff)), 0.0f), 1e-10f);
    o1.x = arn(fmaxf(mrn(acc[i2][4], (float)(mhi & 0xff)), 0.0f), 1e-10f);
    o1.y = arn(fmaxf(mrn(acc[i2][5], (float)((mhi >> 8) & 0xff)), 0.0f), 1e-10f);
    o1.z = arn(fmaxf(mrn(acc[i2][6], (float)((mhi >> 16) & 0xff)), 0.0f), 1e-10f);
    o1.w = arn(fmaxf(mrn(acc[i2][7], (float)((mhi >> 24) & 0xff)), 0.0f), 1e-10f);
    *reinterpret_cast<float4*>(&wout[rb + col0 + tx * 4])      = o0;
    *reinterpret_cast<float4*>(&wout[rb + col0 + 64 + tx * 4]) = o1;
  }
}

// =====================================================================
// Kernel C: t = sigmoid(FMA-chain dot(cur_row, pool))  [sign-critical]
// =====================================================================
__global__ __launch_bounds__(256)
void tz_kernel(const float* __restrict__ cur, const float* __restrict__ pool,
               float* __restrict__ tv, int nrows, int d) {
  int row = blockIdx.x * 256 + threadIdx.x;
  if (row >= nrows) return;
  const float* x = cur + (size_t)row * d;
  float acc = 0.0f;
  for (int k = 0; k < d; ++k) acc = __builtin_fmaf(x[k], pool[k], acc);
  float e = (float)exp(-(double)acc);   // 0.5-ulp proxy for np.exp f32
  tv[row] = __fdiv_rn(1.0f, arn(1.0f, e));
}

// =====================================================================
// Kernel D: per-row {pairwise rowsum DAG, thr, stats partials}; does NOT
// materialize p (phi recomputes it bit-identically from w,rs,thr).
// =====================================================================
__global__ __launch_bounds__(256)
void rowstat_kernel(const float* __restrict__ wbuf, const float* __restrict__ tv,
                    float* __restrict__ rsv, float* __restrict__ thrv,
                    double* __restrict__ cpart, int n) {
  const int row = blockIdx.x;          // b*n + i
  const int t = threadIdx.x;
  const float* a = wbuf + (size_t)row * n;
  const int i = row % n;
  const int kleaf = t >> 4, l = t & 15;
  __shared__ float leaf[16];
  __shared__ float sh_rs, sh_thr;
  {
    const float* base = a + kleaf * 128;
    float r0 = base[l],      r1 = base[16 + l],  r2 = base[32 + l],  r3 = base[48 + l];
    float r4 = base[64 + l], r5 = base[80 + l],  r6 = base[96 + l],  r7 = base[112 + l];
    float v = arn(arn(arn(r0, r1), arn(r2, r3)), arn(arn(r4, r5), arn(r6, r7)));
    v = arn(v, __shfl_xor(v, 8));
    v = arn(v, __shfl_xor(v, 4));
    v = arn(v, __shfl_xor(v, 2));
    v = arn(v, __shfl_xor(v, 1));
    if (l == 0) leaf[kleaf] = v;
  }
  __syncthreads();
  if (t == 0) {
    float t1[8], t2[4], t3[2];
#pragma unroll
    for (int k2 = 0; k2 < 8; ++k2) t1[k2] = arn(leaf[2*k2], leaf[2*k2+1]);
#pragma unroll
    for (int k2 = 0; k2 < 4; ++k2) t2[k2] = arn(t1[2*k2], t1[2*k2+1]);
#pragma unroll
    for (int k2 = 0; k2 < 2; ++k2) t3[k2] = arn(t2[2*k2], t2[2*k2+1]);
    float rs = arn(t3[0], t3[1]);
    float tb = __fdiv_rn(a[i], rs);          // fl(wii/rs)
    float th = mrn(tb, tv[row]);             // fl(tb * t)
    sh_rs = rs; sh_thr = th;
    rsv[row] = rs; thrv[row] = th;
  }
  __syncthreads();
  const float rs = sh_rs, thr = sh_thr;
  double s1 = 0.0, s2 = 0.0;
  for (int off = 0; off < n; off += 1024) {
    float4 wv = *reinterpret_cast<const float4*>(&a[off + t * 4]);
    float wa[4] = {wv.x, wv.y, wv.z, wv.w};
#pragma unroll
    for (int c = 0; c < 4; ++c) {
      float probs = __fdiv_rn(wa[c], rs);
      float x = __fsub_rn(probs, thr);
      if (x >= 0.0f) {
        float pv = __fdiv_rn(1.0f, arn(1.0f, expf(-x)));
        s1 += (double)pv;
        s2 += (double)pv * (double)pv;
      }
    }
  }
  __shared__ double sh1[256], sh2[256];
  sh1[t] = s1; sh2[t] = s2;
  __syncthreads();
  for (int s = 128; s > 0; s >>= 1) {
    if (t < s) { sh1[t] += sh1[t + s]; sh2[t] += sh2[t + s]; }
    __syncthreads();
  }
  if (t == 0) {
    cpart[(size_t)row * 2 + 0] = sh1[0];
    cpart[(size_t)row * 2 + 1] = sh2[0];
  }
}

// =====================================================================
// Kernel E: per-batch mean / inv-std (biased) from per-row partials
// =====================================================================
__global__ __launch_bounds__(256)
void stats_kernel(const double* __restrict__ cpart, float* __restrict__ bstats,
                  int nb, double inv_nn) {
  int b = blockIdx.x, t = threadIdx.x;
  double s1 = 0.0, s2 = 0.0;
  for (int c = t; c < nb; c += 256) {
    s1 += cpart[((size_t)b * nb + c) * 2 + 0];
    s2 += cpart[((size_t)b * nb + c) * 2 + 1];
  }
  __shared__ double sh1[256], sh2[256];
  sh1[t] = s1; sh2[t] = s2;
  __syncthreads();
  for (int s = 128; s > 0; s >>= 1) {
    if (t < s) { sh1[t] += sh1[t + s]; sh2[t] += sh2[t + s]; }
    __syncthreads();
  }
  if (t == 0) {
    double mean = sh1[0] * inv_nn;
    double var = sh2[0] * inv_nn - mean * mean;
    bstats[b * 2 + 0] = (float)mean;
    bstats[b * 2 + 1] = (float)(1.0 / sqrt(var + 1e-5));
  }
}

// =====================================================================
// Kernel F: phi from w in-place. Recomputes probs/x/p with the identical
// f32 op sequence as rowstat (same inputs -> bit-identical sign).
// phi = tau * (x>=0 ? p : 1), tau = expf(2*(gamma*xn+beta)), xn=(p-mean)*inv
// =====================================================================
__global__ __launch_bounds__(256)
void phi_kernel(float4* __restrict__ buf, const float* __restrict__ rsv,
                const float* __restrict__ thrv, const float* __restrict__ bstats,
                const float* __restrict__ gamma, const float* __restrict__ beta,
                size_t total4, int nq, int n) {
  size_t idx = (size_t)blockIdx.x * blockDim.x + threadIdx.x;
  if (idx >= total4) return;
  int row = (int)(idx / (size_t)nq);      // global row b*n + i
  int b = row / n;
  float rs = rsv[row], thr = thrv[row];
  float mean = bstats[b * 2 + 0];
  float inv = bstats[b * 2 + 1];
  float ga = gamma[0] * 2.0f;
  float be = beta[0] * 2.0f;
  float4 v = buf[idx];
  float wa[4] = {v.x, v.y, v.z, v.w};
  float oa[4];
#pragma unroll
  for (int c = 0; c < 4; ++c) {
    float probs = __fdiv_rn(wa[c], rs);
    float x = __fsub_rn(probs, thr);
    float p = 0.0f, m = 1.0f;
    if (x >= 0.0f) {
      p = __fdiv_rn(1.0f, arn(1.0f, expf(-x)));
      m = p;
    }
    float xn = (p - mean) * inv;
    oa[c] = expf(ga * xn + be) * m;
  }
  v.x = oa[0]; v.y = oa[1]; v.z = oa[2]; v.w = oa[3];
  buf[idx] = v;
}

extern "C" void kernel_launch(void* const* d_in, const int* in_sizes, int n_in,
                              void* d_out, int out_size, void* d_ws, size_t ws_size,
                              hipStream_t stream) {
  const float* S     = (const float*)d_in[0];
  const float* cur   = (const float*)d_in[1];
  const float* prev  = (const float*)d_in[2];
  const float* pool  = (const float*)d_in[3];
  const float* gamma = (const float*)d_in[4];
  const float* beta  = (const float*)d_in[5];
  const int d = in_sizes[3];
  const int n = in_sizes[0] / d;
  const int b = in_sizes[1] / (n * d);
  float* out = (float*)d_out;

  const int nrows = b * n;

  char* ws = (char*)d_ws;
  float* tv   = (float*)ws; ws += (size_t)nrows * sizeof(float);
  float* rsv  = (float*)ws; ws += (size_t)nrows * sizeof(float);
  float* thrv = (float*)ws; ws += (size_t)nrows * sizeof(float);
  ws = (char*)(((uintptr_t)ws + 15) & ~(uintptr_t)15);
  double* cpart = (double*)ws; ws += (size_t)nrows * 2 * sizeof(double);
  float* bstats = (float*)ws;  ws += 64;
  unsigned char* mask = (unsigned char*)ws;   // n*n bytes

  dim3 blk(256);

  hipLaunchKernelGGL(mask_kernel, dim3(n / 128, n / 128), blk, 0, stream, S, mask, n, d);
  hipLaunchKernelGGL(tz_kernel, dim3((nrows + 255) / 256), blk, 0, stream,
                     cur, pool, tv, nrows, d);
  hipLaunchKernelGGL(graph_kernel, dim3(n / 128, n / 128, b), blk, 0, stream,
                     cur, prev, mask, out, n, d);
  hipLaunchKernelGGL(rowstat_kernel, dim3(nrows), blk, 0, stream,
                     out, tv, rsv, thrv, cpart, n);
  hipLaunchKernelGGL(stats_kernel, dim3(b), blk, 0, stream,
                     cpart, bstats, n, 1.0 / ((double)n * (double)n));
  size_t total4 = (size_t)b * n * n / 4;
  hipLaunchKernelGGL(phi_kernel, dim3((unsigned)((total4 + 255) / 256)), blk, 0, stream,
                     (float4*)out, rsv, thrv, bstats, gamma, beta, total4, n / 4, n);
}

// Round 9
// 362.830 us; speedup vs baseline: 1.2471x; 1.2471x over previous
//
#include <hip/hip_runtime.h>
#include <math.h>
#include <stdint.h>

// ============================================================================
// Numerics contract (DO NOT CHANGE — rounds 6/7/8 passed with exactly this):
//  * every sign-critical dot product = BLAS sgemm per-element DAG:
//    acc=0; for k=0..d-1 ascending: acc = fmaf(a,b,acc)  (single acc, fused)
//  * row sums = numpy pairwise_sum avx512f replica (16 leaves of 128, 8x16-lane
//    accs, ((r0+r1)+(r2+r3))+((r4+r5)+(r6+r7)), reduce_add xor-tree 8/4/2/1,
//    perfect binary tree over leaves)
//  * thr = fl(fl(wii/rs) * tv);  x = fl(fl(w/rs) - thr);  pos iff x >= 0
//  * tz sigmoid via double-exp (feeds thr -> sign-critical)
// float2 packing below only changes instruction encoding (v_pk_fma_f32 =
// two independent per-lane fused FMAs); per-element chains are unchanged.
// ============================================================================

typedef float f32x2 __attribute__((ext_vector_type(2)));

__device__ __forceinline__ float mrn(float a, float b) { return __fmul_rn(a, b); }
__device__ __forceinline__ float arn(float a, float b) { return __fadd_rn(a, b); }

#define GBK 16

// =====================================================================
// Kernel A: static mask. 128x128 tile, 8x8/thread, single-buffer LDS
// (R7 structure), packed-f32 inner loop. mask = (S S^T > 0).
// =====================================================================
__global__ __launch_bounds__(256)
void mask_kernel(const float* __restrict__ S, unsigned char* __restrict__ mask,
                 int n, int d) {
  __shared__ float Xk[GBK][132];
  __shared__ float Yk[GBK][132];
  const int t = threadIdx.x, tx = t & 15, ty = t >> 4;
  const int row0 = blockIdx.y * 128, col0 = blockIdx.x * 128;
  const int r = t >> 1, q = t & 1;
  f32x2 acc[8][4] = {};
  for (int kc = 0; kc < d; kc += GBK) {
    __syncthreads();
    const float* xp = &S[(size_t)(row0 + r) * d + kc + q * 8];
    float4 v0 = *reinterpret_cast<const float4*>(xp);
    float4 v1 = *reinterpret_cast<const float4*>(xp + 4);
    const float* yp = &S[(size_t)(col0 + r) * d + kc + q * 8];
    float4 u0 = *reinterpret_cast<const float4*>(yp);
    float4 u1 = *reinterpret_cast<const float4*>(yp + 4);
    Xk[q*8+0][r] = v0.x; Xk[q*8+1][r] = v0.y; Xk[q*8+2][r] = v0.z; Xk[q*8+3][r] = v0.w;
    Xk[q*8+4][r] = v1.x; Xk[q*8+5][r] = v1.y; Xk[q*8+6][r] = v1.z; Xk[q*8+7][r] = v1.w;
    Yk[q*8+0][r] = u0.x; Yk[q*8+1][r] = u0.y; Yk[q*8+2][r] = u0.z; Yk[q*8+3][r] = u0.w;
    Yk[q*8+4][r] = u1.x; Yk[q*8+5][r] = u1.y; Yk[q*8+6][r] = u1.z; Yk[q*8+7][r] = u1.w;
    __syncthreads();
#pragma unroll
    for (int k = 0; k < GBK; ++k) {
      float4 a0 = *reinterpret_cast<const float4*>(&Xk[k][ty * 8]);
      float4 a1 = *reinterpret_cast<const float4*>(&Xk[k][ty * 8 + 4]);
      float4 b0 = *reinterpret_cast<const float4*>(&Yk[k][tx * 4]);
      float4 b1 = *reinterpret_cast<const float4*>(&Yk[k][64 + tx * 4]);
      float a[8] = {a0.x, a0.y, a0.z, a0.w, a1.x, a1.y, a1.z, a1.w};
      f32x2 b2[4];
      b2[0].x = b0.x; b2[0].y = b0.y; b2[1].x = b0.z; b2[1].y = b0.w;
      b2[2].x = b1.x; b2[2].y = b1.y; b2[3].x = b1.z; b2[3].y = b1.w;
#pragma unroll
      for (int i2 = 0; i2 < 8; ++i2) {
        f32x2 av; av.x = a[i2]; av.y = a[i2];
#pragma unroll
        for (int j = 0; j < 4; ++j)
          acc[i2][j] = __builtin_elementwise_fma(av, b2[j], acc[i2][j]);
      }
    }
  }
#pragma unroll
  for (int i2 = 0; i2 < 8; ++i2) {
    int gi = row0 + ty * 8 + i2;
    unsigned lo = 0, hi = 0;
    lo |= (acc[i2][0].x > 0.0f ? 1u : 0u);
    lo |= (acc[i2][0].y > 0.0f ? 1u : 0u) << 8;
    lo |= (acc[i2][1].x > 0.0f ? 1u : 0u) << 16;
    lo |= (acc[i2][1].y > 0.0f ? 1u : 0u) << 24;
    hi |= (acc[i2][2].x > 0.0f ? 1u : 0u);
    hi |= (acc[i2][2].y > 0.0f ? 1u : 0u) << 8;
    hi |= (acc[i2][3].x > 0.0f ? 1u : 0u) << 16;
    hi |= (acc[i2][3].y > 0.0f ? 1u : 0u) << 24;
    *reinterpret_cast<unsigned*>(&mask[(size_t)gi * n + col0 + tx * 4])      = lo;
    *reinterpret_cast<unsigned*>(&mask[(size_t)gi * n + col0 + 64 + tx * 4]) = hi;
  }
}

// =====================================================================
// Kernel B: graph GEMM, R7 structure + packed-f32; w = relu(g*mask)+1e-10
// =====================================================================
__global__ __launch_bounds__(256)
void graph_kernel(const float* __restrict__ cur_, const float* __restrict__ prev,
                  const unsigned char* __restrict__ mask, float* __restrict__ wout,
                  int n, int d) {
  __shared__ float Xk[GBK][132];
  __shared__ float Yk[GBK][132];
  const int t = threadIdx.x, tx = t & 15, ty = t >> 4;
  const int row0 = blockIdx.y * 128, col0 = blockIdx.x * 128, bz = blockIdx.z;
  const float* X = cur_ + (size_t)bz * n * d;
  const float* Y = prev + (size_t)bz * n * d;
  const int r = t >> 1, q = t & 1;
  f32x2 acc[8][4] = {};
  for (int kc = 0; kc < d; kc += GBK) {
    __syncthreads();
    const float* xp = &X[(size_t)(row0 + r) * d + kc + q * 8];
    float4 v0 = *reinterpret_cast<const float4*>(xp);
    float4 v1 = *reinterpret_cast<const float4*>(xp + 4);
    const float* yp = &Y[(size_t)(col0 + r) * d + kc + q * 8];
    float4 u0 = *reinterpret_cast<const float4*>(yp);
    float4 u1 = *reinterpret_cast<const float4*>(yp + 4);
    Xk[q*8+0][r] = v0.x; Xk[q*8+1][r] = v0.y; Xk[q*8+2][r] = v0.z; Xk[q*8+3][r] = v0.w;
    Xk[q*8+4][r] = v1.x; Xk[q*8+5][r] = v1.y; Xk[q*8+6][r] = v1.z; Xk[q*8+7][r] = v1.w;
    Yk[q*8+0][r] = u0.x; Yk[q*8+1][r] = u0.y; Yk[q*8+2][r] = u0.z; Yk[q*8+3][r] = u0.w;
    Yk[q*8+4][r] = u1.x; Yk[q*8+5][r] = u1.y; Yk[q*8+6][r] = u1.z; Yk[q*8+7][r] = u1.w;
    __syncthreads();
#pragma unroll
    for (int k = 0; k < GBK; ++k) {
      float4 a0 = *reinterpret_cast<const float4*>(&Xk[k][ty * 8]);
      float4 a1 = *reinterpret_cast<const float4*>(&Xk[k][ty * 8 + 4]);
      float4 b0 = *reinterpret_cast<const float4*>(&Yk[k][tx * 4]);
      float4 b1 = *reinterpret_cast<const float4*>(&Yk[k][64 + tx * 4]);
      float a[8] = {a0.x, a0.y, a0.z, a0.w, a1.x, a1.y, a1.z, a1.w};
      f32x2 b2[4];
      b2[0].x = b0.x; b2[0].y = b0.y; b2[1].x = b0.z; b2[1].y = b0.w;
      b2[2].x = b1.x; b2[2].y = b1.y; b2[3].x = b1.z; b2[3].y = b1.w;
#pragma unroll
      for (int i2 = 0; i2 < 8; ++i2) {
        f32x2 av; av.x = a[i2]; av.y = a[i2];
#pragma unroll
        for (int j = 0; j < 4; ++j)
          acc[i2][j] = __builtin_elementwise_fma(av, b2[j], acc[i2][j]);
      }
    }
  }
#pragma unroll
  for (int i2 = 0; i2 < 8; ++i2) {
    int gi = row0 + ty * 8 + i2;
    size_t rb = (size_t)bz * n * n + (size_t)gi * n;
    unsigned mlo = *reinterpret_cast<const unsigned*>(&mask[(size_t)gi * n + col0 + tx * 4]);
    unsigned mhi = *reinterpret_cast<const unsigned*>(&mask[(size_t)gi * n + col0 + 64 + tx * 4]);
    float4 o0, o1;
    o0.x = arn(fmaxf(mrn(acc[i2][0].x, (float)(mlo & 0xff)), 0.0f), 1e-10f);
    o0.y = arn(fmaxf(mrn(acc[i2][0].y, (float)((mlo >> 8) & 0xff)), 0.0f), 1e-10f);
    o0.z = arn(fmaxf(mrn(acc[i2][1].x, (float)((mlo >> 16) & 0xff)), 0.0f), 1e-10f);
    o0.w = arn(fmaxf(mrn(acc[i2][1].y, (float)((mlo >> 24) & 0xff)), 0.0f), 1e-10f);
    o1.x = arn(fmaxf(mrn(acc[i2][2].x, (float)(mhi & 0xff)), 0.0f), 1e-10f);
    o1.y = arn(fmaxf(mrn(acc[i2][2].y, (float)((mhi >> 8) & 0xff)), 0.0f), 1e-10f);
    o1.z = arn(fmaxf(mrn(acc[i2][3].x, (float)((mhi >> 16) & 0xff)), 0.0f), 1e-10f);
    o1.w = arn(fmaxf(mrn(acc[i2][3].y, (float)((mhi >> 24) & 0xff)), 0.0f), 1e-10f);
    *reinterpret_cast<float4*>(&wout[rb + col0 + tx * 4])      = o0;
    *reinterpret_cast<float4*>(&wout[rb + col0 + 64 + tx * 4]) = o1;
  }
}

// =====================================================================
// Kernel C: t = sigmoid(FMA-chain dot(cur_row, pool))  [sign-critical]
// =====================================================================
__global__ __launch_bounds__(256)
void tz_kernel(const float* __restrict__ cur, const float* __restrict__ pool,
               float* __restrict__ tv, int nrows, int d) {
  int row = blockIdx.x * 256 + threadIdx.x;
  if (row >= nrows) return;
  const float* x = cur + (size_t)row * d;
  float acc = 0.0f;
  for (int k = 0; k < d; ++k) acc = __builtin_fmaf(x[k], pool[k], acc);
  float e = (float)exp(-(double)acc);   // 0.5-ulp proxy for np.exp f32
  tv[row] = __fdiv_rn(1.0f, arn(1.0f, e));
}

// =====================================================================
// Kernel D: per-row {pairwise rowsum DAG, thr, stats partials}; does NOT
// materialize p (phi recomputes it bit-identically from w,rs,thr).
// =====================================================================
__global__ __launch_bounds__(256)
void rowstat_kernel(const float* __restrict__ wbuf, const float* __restrict__ tv,
                    float* __restrict__ rsv, float* __restrict__ thrv,
                    double* __restrict__ cpart, int n) {
  const int row = blockIdx.x;          // b*n + i
  const int t = threadIdx.x;
  const float* a = wbuf + (size_t)row * n;
  const int i = row % n;
  const int kleaf = t >> 4, l = t & 15;
  __shared__ float leaf[16];
  __shared__ float sh_rs, sh_thr;
  {
    const float* base = a + kleaf * 128;
    float r0 = base[l],      r1 = base[16 + l],  r2 = base[32 + l],  r3 = base[48 + l];
    float r4 = base[64 + l], r5 = base[80 + l],  r6 = base[96 + l],  r7 = base[112 + l];
    float v = arn(arn(arn(r0, r1), arn(r2, r3)), arn(arn(r4, r5), arn(r6, r7)));
    v = arn(v, __shfl_xor(v, 8));
    v = arn(v, __shfl_xor(v, 4));
    v = arn(v, __shfl_xor(v, 2));
    v = arn(v, __shfl_xor(v, 1));
    if (l == 0) leaf[kleaf] = v;
  }
  __syncthreads();
  if (t == 0) {
    float t1[8], t2[4], t3[2];
#pragma unroll
    for (int k2 = 0; k2 < 8; ++k2) t1[k2] = arn(leaf[2*k2], leaf[2*k2+1]);
#pragma unroll
    for (int k2 = 0; k2 < 4; ++k2) t2[k2] = arn(t1[2*k2], t1[2*k2+1]);
#pragma unroll
    for (int k2 = 0; k2 < 2; ++k2) t3[k2] = arn(t2[2*k2], t2[2*k2+1]);
    float rs = arn(t3[0], t3[1]);
    float tb = __fdiv_rn(a[i], rs);          // fl(wii/rs)
    float th = mrn(tb, tv[row]);             // fl(tb * t)
    sh_rs = rs; sh_thr = th;
    rsv[row] = rs; thrv[row] = th;
  }
  __syncthreads();
  const float rs = sh_rs, thr = sh_thr;
  double s1 = 0.0, s2 = 0.0;
  for (int off = 0; off < n; off += 1024) {
    float4 wv = *reinterpret_cast<const float4*>(&a[off + t * 4]);
    float wa[4] = {wv.x, wv.y, wv.z, wv.w};
#pragma unroll
    for (int c = 0; c < 4; ++c) {
      float probs = __fdiv_rn(wa[c], rs);
      float x = __fsub_rn(probs, thr);
      if (x >= 0.0f) {
        float pv = __fdiv_rn(1.0f, arn(1.0f, expf(-x)));
        s1 += (double)pv;
        s2 += (double)pv * (double)pv;
      }
    }
  }
  __shared__ double sh1[256], sh2[256];
  sh1[t] = s1; sh2[t] = s2;
  __syncthreads();
  for (int s = 128; s > 0; s >>= 1) {
    if (t < s) { sh1[t] += sh1[t + s]; sh2[t] += sh2[t + s]; }
    __syncthreads();
  }
  if (t == 0) {
    cpart[(size_t)row * 2 + 0] = sh1[0];
    cpart[(size_t)row * 2 + 1] = sh2[0];
  }
}

// =====================================================================
// Kernel E: per-batch mean / inv-std (biased) from per-row partials
// =====================================================================
__global__ __launch_bounds__(256)
void stats_kernel(const double* __restrict__ cpart, float* __restrict__ bstats,
                  int nb, double inv_nn) {
  int b = blockIdx.x, t = threadIdx.x;
  double s1 = 0.0, s2 = 0.0;
  for (int c = t; c < nb; c += 256) {
    s1 += cpart[((size_t)b * nb + c) * 2 + 0];
    s2 += cpart[((size_t)b * nb + c) * 2 + 1];
  }
  __shared__ double sh1[256], sh2[256];
  sh1[t] = s1; sh2[t] = s2;
  __syncthreads();
  for (int s = 128; s > 0; s >>= 1) {
    if (t < s) { sh1[t] += sh1[t + s]; sh2[t] += sh2[t + s]; }
    __syncthreads();
  }
  if (t == 0) {
    double mean = sh1[0] * inv_nn;
    double var = sh2[0] * inv_nn - mean * mean;
    bstats[b * 2 + 0] = (float)mean;
    bstats[b * 2 + 1] = (float)(1.0 / sqrt(var + 1e-5));
  }
}

// =====================================================================
// Kernel F: phi from w in-place. Recomputes probs/x/p with the identical
// f32 op sequence as rowstat (same inputs -> bit-identical sign).
// =====================================================================
__global__ __launch_bounds__(256)
void phi_kernel(float4* __restrict__ buf, const float* __restrict__ rsv,
                const float* __restrict__ thrv, const float* __restrict__ bstats,
                const float* __restrict__ gamma, const float* __restrict__ beta,
                size_t total4, int nq, int n) {
  size_t idx = (size_t)blockIdx.x * blockDim.x + threadIdx.x;
  if (idx >= total4) return;
  int row = (int)(idx / (size_t)nq);      // global row b*n + i
  int b = row / n;
  float rs = rsv[row], thr = thrv[row];
  float mean = bstats[b * 2 + 0];
  float inv = bstats[b * 2 + 1];
  float ga = gamma[0] * 2.0f;
  float be = beta[0] * 2.0f;
  float4 v = buf[idx];
  float wa[4] = {v.x, v.y, v.z, v.w};
  float oa[4];
#pragma unroll
  for (int c = 0; c < 4; ++c) {
    float probs = __fdiv_rn(wa[c], rs);
    float x = __fsub_rn(probs, thr);
    float p = 0.0f, m = 1.0f;
    if (x >= 0.0f) {
      p = __fdiv_rn(1.0f, arn(1.0f, expf(-x)));
      m = p;
    }
    float xn = (p - mean) * inv;
    oa[c] = expf(ga * xn + be) * m;
  }
  v.x = oa[0]; v.y = oa[1]; v.z = oa[2]; v.w = oa[3];
  buf[idx] = v;
}

extern "C" void kernel_launch(void* const* d_in, const int* in_sizes, int n_in,
                              void* d_out, int out_size, void* d_ws, size_t ws_size,
                              hipStream_t stream) {
  const float* S     = (const float*)d_in[0];
  const float* cur   = (const float*)d_in[1];
  const float* prev  = (const float*)d_in[2];
  const float* pool  = (const float*)d_in[3];
  const float* gamma = (const float*)d_in[4];
  const float* beta  = (const float*)d_in[5];
  const int d = in_sizes[3];
  const int n = in_sizes[0] / d;
  const int b = in_sizes[1] / (n * d);
  float* out = (float*)d_out;

  const int nrows = b * n;

  char* ws = (char*)d_ws;
  float* tv   = (float*)ws; ws += (size_t)nrows * sizeof(float);
  float* rsv  = (float*)ws; ws += (size_t)nrows * sizeof(float);
  float* thrv = (float*)ws; ws += (size_t)nrows * sizeof(float);
  ws = (char*)(((uintptr_t)ws + 15) & ~(uintptr_t)15);
  double* cpart = (double*)ws; ws += (size_t)nrows * 2 * sizeof(double);
  float* bstats = (float*)ws;  ws += 64;
  unsigned char* mask = (unsigned char*)ws;   // n*n bytes

  dim3 blk(256);

  hipLaunchKernelGGL(mask_kernel, dim3(n / 128, n / 128), blk, 0, stream, S, mask, n, d);
  hipLaunchKernelGGL(tz_kernel, dim3((nrows + 255) / 256), blk, 0, stream,
                     cur, pool, tv, nrows, d);
  hipLaunchKernelGGL(graph_kernel, dim3(n / 128, n / 128, b), blk, 0, stream,
                     cur, prev, mask, out, n, d);
  hipLaunchKernelGGL(rowstat_kernel, dim3(nrows), blk, 0, stream,
                     out, tv, rsv, thrv, cpart, n);
  hipLaunchKernelGGL(stats_kernel, dim3(b), blk, 0, stream,
                     cpart, bstats, n, 1.0 / ((double)n * (double)n));
  size_t total4 = (size_t)b * n * n / 4;
  hipLaunchKernelGGL(phi_kernel, dim3((unsigned)((total4 + 255) / 256)), blk, 0, stream,
                     (float4*)out, rsv, thrv, bstats, gamma, beta, total4, n / 4, n);
}